// Round 2
// baseline (1719.618 us; speedup 1.0000x reference)
//
#include <hip/hip_runtime.h>

// Only the temporal (LSTM) branch of the reference reaches the output
// (h_gcn is dead). Per node:
//   xt_s = x[n, 52+s] * W_tp + b_tp   (rank-1, folded into pre[] by precomp)
//   2-layer LSTM (H=32, T=12, torch gate order i,f,g,o)
//   out[n] = relu(h1 @ W_fc1 + b_fc1) @ W_fc2 + b_fc2
//
// Round-2 structure: 4 waves per 64 nodes. Wave p computes gate rows
// j in [8p, 8p+8) for all 64 nodes of the block -> j is wave-uniform ->
// weights stay SGPR scalar-broadcast loads. h-state exchanged across the
// 4 waves through LDS (stride-48 rows: 16B-aligned float4, 2-way bank
// aliasing = free). c-state in registers (jj fully unrolled).

#define TSTEPS 12
#define ROWF 48   // LDS row stride in floats: 16B-aligned, 2-way bank alias

__device__ __forceinline__ float fsig(float x) {
    float e = __expf(-x);
    return __builtin_amdgcn_rcpf(1.0f + e);
}

__device__ __forceinline__ float ftanh(float x) {
    float ax = fabsf(x);
    float e = __expf(-2.0f * ax);              // in (0,1], no overflow
    float r = (1.0f - e) * __builtin_amdgcn_rcpf(1.0f + e);
    return x < 0.0f ? -r : r;
}

// pre layout: [0:128) A0 (x coefficient per gate row), [128:256) C0 (bias),
// [256:384) C1 (layer-1 bias)
__global__ void precomp_kernel(const float* __restrict__ Wih0,
                               const float* __restrict__ Wtp,
                               const float* __restrict__ btp,
                               const float* __restrict__ bih0,
                               const float* __restrict__ bhh0,
                               const float* __restrict__ bih1,
                               const float* __restrict__ bhh1,
                               float* __restrict__ ws) {
    int r = threadIdx.x;   // 0..127
    if (r < 128) {
        float a = 0.0f, c = 0.0f;
#pragma unroll
        for (int k = 0; k < 16; ++k) {
            float w = Wih0[r * 16 + k];
            a += w * Wtp[k];
            c += w * btp[k];
        }
        ws[r]       = a;
        ws[128 + r] = c + bih0[r] + bhh0[r];
        ws[256 + r] = bih1[r] + bhh1[r];
    }
}

__global__ __launch_bounds__(256, 3) void lstm_kernel(
    const float* __restrict__ x,
    const float* __restrict__ Whh0,   // [128,32]
    const float* __restrict__ Wih1,   // [128,32]
    const float* __restrict__ Whh1,   // [128,32]
    const float* __restrict__ Wfc1,   // [32,16]
    const float* __restrict__ bfc1,   // [16]
    const float* __restrict__ Wfc2,   // [16]
    const float* __restrict__ bfc2,   // [1]
    const float* __restrict__ pre,    // [384]
    float* __restrict__ out, int N)
{
    __shared__ float bufH0[64 * ROWF];
    __shared__ float bufH1[64 * ROWF];

    const int tid  = threadIdx.x;
    const int lane = tid & 63;
    // wave id: force SGPR so weight addressing is provably wave-uniform
    const int p    = __builtin_amdgcn_readfirstlane(tid >> 6);
    const int jb   = p * 8;                   // this wave's gate-row base
    const int n    = blockIdx.x * 64 + lane;  // node (same set for all 4 waves)
    const int nn   = (n < N) ? n : (N > 0 ? N - 1 : 0);
    const float* xr = x + (size_t)nn * 64 + 52;

    float h0[32], h1[32], c0[8], c1[8];
#pragma unroll
    for (int k = 0; k < 32; ++k) { h0[k] = 0.0f; h1[k] = 0.0f; }
#pragma unroll
    for (int k = 0; k < 8; ++k)  { c0[k] = 0.0f; c1[k] = 0.0f; }

    float* myrow0 = &bufH0[lane * ROWF];
    float* myrow1 = &bufH1[lane * ROWF];

    float xval = xr[0];

#pragma unroll 1
    for (int t = 0; t < TSTEPS; ++t) {
        // prefetch next x early; latency hidden behind this step's compute
        const float xnext = xr[(t < TSTEPS - 1) ? (t + 1) : (TSTEPS - 1)];

        float hn[8];

        // ---------------- layer 0: rows jb..jb+7 ----------------
#pragma unroll
        for (int jj = 0; jj < 8; ++jj) {
            const int j = jb + jj;
            float gi = pre[128 + j]      + xval * pre[j];
            float gf = pre[128 + 32 + j] + xval * pre[32 + j];
            float gg = pre[128 + 64 + j] + xval * pre[64 + j];
            float go = pre[128 + 96 + j] + xval * pre[96 + j];
            const float* w = Whh0 + j * 32;   // rows j, j+32, j+64, j+96
#pragma unroll
            for (int k = 0; k < 32; ++k) {
                const float hk = h0[k];
                gi += w[k]        * hk;
                gf += w[1024 + k] * hk;
                gg += w[2048 + k] * hk;
                go += w[3072 + k] * hk;
            }
            const float cc = fsig(gf) * c0[jj] + fsig(gi) * ftanh(gg);
            c0[jj] = cc;
            hn[jj] = fsig(go) * ftanh(cc);
        }
        // exchange new h0 across the 4 waves
        {
            float4* wv = reinterpret_cast<float4*>(myrow0 + jb);
            wv[0] = make_float4(hn[0], hn[1], hn[2], hn[3]);
            wv[1] = make_float4(hn[4], hn[5], hn[6], hn[7]);
        }
        __syncthreads();
        {
            const float4* rv = reinterpret_cast<const float4*>(myrow0);
#pragma unroll
            for (int q = 0; q < 8; ++q) {
                const float4 v = rv[q];
                h0[q * 4 + 0] = v.x; h0[q * 4 + 1] = v.y;
                h0[q * 4 + 2] = v.z; h0[q * 4 + 3] = v.w;
            }
        }

        // ---------------- layer 1: rows jb..jb+7 ----------------
#pragma unroll
        for (int jj = 0; jj < 8; ++jj) {
            const int j = jb + jj;
            float gi = pre[256 + j];
            float gf = pre[256 + 32 + j];
            float gg = pre[256 + 64 + j];
            float go = pre[256 + 96 + j];
            const float* wi = Wih1 + j * 32;
            const float* wh = Whh1 + j * 32;
#pragma unroll
            for (int k = 0; k < 32; ++k) {
                const float ak = h0[k];
                const float bk = h1[k];
                gi += wi[k]        * ak + wh[k]        * bk;
                gf += wi[1024 + k] * ak + wh[1024 + k] * bk;
                gg += wi[2048 + k] * ak + wh[2048 + k] * bk;
                go += wi[3072 + k] * ak + wh[3072 + k] * bk;
            }
            const float cc = fsig(gf) * c1[jj] + fsig(gi) * ftanh(gg);
            c1[jj] = cc;
            hn[jj] = fsig(go) * ftanh(cc);
        }
        // exchange new h1 across the 4 waves
        {
            float4* wv = reinterpret_cast<float4*>(myrow1 + jb);
            wv[0] = make_float4(hn[0], hn[1], hn[2], hn[3]);
            wv[1] = make_float4(hn[4], hn[5], hn[6], hn[7]);
        }
        __syncthreads();
        {
            const float4* rv = reinterpret_cast<const float4*>(myrow1);
#pragma unroll
            for (int q = 0; q < 8; ++q) {
                const float4 v = rv[q];
                h1[q * 4 + 0] = v.x; h1[q * 4 + 1] = v.y;
                h1[q * 4 + 2] = v.z; h1[q * 4 + 3] = v.w;
            }
        }

        xval = xnext;
    }

    // epilogue: relu(h1 @ Wfc1 + bfc1) @ Wfc2 + bfc2 — wave 0 only
    if (p == 0 && n < N) {
        float acc = bfc2[0];
#pragma unroll 1
        for (int m = 0; m < 16; ++m) {
            float a = bfc1[m];
#pragma unroll
            for (int k = 0; k < 32; ++k) a += h1[k] * Wfc1[k * 16 + m];
            acc += fmaxf(a, 0.0f) * Wfc2[m];
        }
        out[n] = acc;
    }
}

extern "C" void kernel_launch(void* const* d_in, const int* in_sizes, int n_in,
                              void* d_out, int out_size, void* d_ws, size_t ws_size,
                              hipStream_t stream) {
    (void)n_in; (void)out_size; (void)ws_size;
    const float* x    = (const float*)d_in[0];
    const float* Wtp  = (const float*)d_in[10];
    const float* btp  = (const float*)d_in[11];
    const float* Wih0 = (const float*)d_in[12];
    const float* Whh0 = (const float*)d_in[13];
    const float* bih0 = (const float*)d_in[14];
    const float* bhh0 = (const float*)d_in[15];
    const float* Wih1 = (const float*)d_in[16];
    const float* Whh1 = (const float*)d_in[17];
    const float* bih1 = (const float*)d_in[18];
    const float* bhh1 = (const float*)d_in[19];
    const float* Wfc1 = (const float*)d_in[20];
    const float* bfc1 = (const float*)d_in[21];
    const float* Wfc2 = (const float*)d_in[22];
    const float* bfc2 = (const float*)d_in[23];

    float* out = (float*)d_out;
    float* pre = (float*)d_ws;   // 384 floats

    const int N = in_sizes[0] / 64;

    precomp_kernel<<<1, 128, 0, stream>>>(Wih0, Wtp, btp, bih0, bhh0, bih1, bhh1, pre);

    const int nblocks = (N + 63) / 64;
    lstm_kernel<<<nblocks, 256, 0, stream>>>(
        x, Whh0, Wih1, Whh1, Wfc1, bfc1, Wfc2, bfc2, pre, out, N);
}